// Round 10
// baseline (190.291 us; speedup 1.0000x reference)
//
#include <hip/hip_runtime.h>
#include <hip/hip_bf16.h>

typedef _Float16 half_t;
typedef __attribute__((ext_vector_type(8))) _Float16 half8;
typedef __attribute__((ext_vector_type(4))) _Float16 half4;
typedef __attribute__((ext_vector_type(4))) float float4v;

#define BSZ 8192
#define NT 1024  // 16 waves/block -> 4 waves/SIMD at grid=256 (1 block/CU)

__device__ __forceinline__ float elu_fast(float v) {
    return v > 0.f ? v : (__expf(v) - 1.f);  // |err| ~1e-7, threshold 1.7e-3
}

// One wave = one 16-col strip (wv < NSTR), NPASS expert-passes of EXPP experts.
// Flat (pass,chunk) pipeline: B(it+2) register-prefetch (3 rotating buffers,
// crosses pass boundary), A(it+1) from LDS double-buffered. Pass-0 coef-mix
// kept in 8 regs; pass-1 adds, ELU, store — same wave, no barrier, no LDS spill.
// Register budget (EXPP=4): bb 48 + acc 32 + aa 16 + part 8 + addr ~= 115.
// amdgpu_waves_per_eu(4,4) pins the VGPR budget at 128 (launch_bounds min alone
// let the backend target 8 waves/EU -> 64 VGPRs -> scratch spill; r8/r9 bug).
// DST 0: fp16->LDS (ACT=ELU opt). DST 2: fp32->global.
template <int EXPP, int NPASS, int CH, int NSTR, int ACT, int DST>
__device__ __forceinline__ void layer_run(
    const half_t* sSrc, int sstr, const half_t* __restrict__ W, int Npad,
    const float* __restrict__ bias, int biasN, const float* sCf,
    half_t* sDst, int dstr, float* __restrict__ gOut, int ldg,
    int row0, int wv, int l15, int quad) {
    if (wv >= NSTR) return;
    constexpr int K = CH * 32;
    constexpr int TOT = NPASS * CH;
    const size_t estr = (size_t)Npad * K;
    const half_t* wbase = &W[(size_t)(wv * 16 + l15) * K + quad * 8];

    half8 bb[3][EXPP];
    half8 aa[2][2];
    float4v acc[EXPP][2];
    float part[2][4];

    // Preload B(0), B(1), A(0)
#pragma unroll
    for (int e = 0; e < EXPP; ++e) bb[0][e] = *(const half8*)&wbase[(size_t)e * estr];
    {
        const half_t* wp = wbase + 32;  // it=1 is (h=0,c=1): CH>=5 always
#pragma unroll
        for (int e = 0; e < EXPP; ++e) bb[1][e] = *(const half8*)&wp[(size_t)e * estr];
    }
    aa[0][0] = *(const half8*)&sSrc[l15 * sstr + quad * 8];
    aa[0][1] = *(const half8*)&sSrc[(16 + l15) * sstr + quad * 8];

#pragma unroll
    for (int it = 0; it < TOT; ++it) {
        const int h = it / CH, c = it - h * CH;
        if (it + 2 < TOT) {  // issue B(it+2) before compute(it)
            const int h2 = (it + 2) / CH, c2 = (it + 2) % CH;
            const half_t* wp = wbase + (size_t)(h2 * EXPP) * estr + c2 * 32;
#pragma unroll
            for (int e = 0; e < EXPP; ++e)
                bb[(it + 2) % 3][e] = *(const half8*)&wp[(size_t)e * estr];
        }
        if (it + 1 < TOT) {  // A(it+1) from LDS (pass 1 re-reads chunk 0..CH-1)
            const int c1n = (it + 1) % CH;
            aa[(it + 1) & 1][0] = *(const half8*)&sSrc[l15 * sstr + c1n * 32 + quad * 8];
            aa[(it + 1) & 1][1] =
                *(const half8*)&sSrc[(16 + l15) * sstr + c1n * 32 + quad * 8];
        }
        if (c == 0) {
#pragma unroll
            for (int e = 0; e < EXPP; ++e) {
                acc[e][0] = (float4v){0.f, 0.f, 0.f, 0.f};
                acc[e][1] = (float4v){0.f, 0.f, 0.f, 0.f};
            }
        }
#pragma unroll
        for (int e = 0; e < EXPP; ++e) {
            acc[e][0] = __builtin_amdgcn_mfma_f32_16x16x32_f16(aa[it & 1][0], bb[it % 3][e],
                                                               acc[e][0], 0, 0, 0);
            acc[e][1] = __builtin_amdgcn_mfma_f32_16x16x32_f16(aa[it & 1][1], bb[it % 3][e],
                                                               acc[e][1], 0, 0, 0);
        }
        if (c == CH - 1) {  // end of pass h (next pass's loads already in flight)
            const int col = wv * 16 + l15;
            const int eoff = h * EXPP;
            float bv[EXPP];
#pragma unroll
            for (int e = 0; e < EXPP; ++e) bv[e] = bias[(eoff + e) * biasN + col];
#pragma unroll
            for (int mt = 0; mt < 2; ++mt)
#pragma unroll
                for (int r = 0; r < 4; ++r) {
                    const int rl = mt * 16 + quad * 4 + r;
                    float val;
                    if (EXPP == 1) {
                        val = acc[0][mt][r] + bv[0];
                    } else {
                        val = 0.f;
#pragma unroll
                        for (int e = 0; e < EXPP; ++e)
                            val += sCf[rl * 8 + eoff + e] * (acc[e][mt][r] + bv[e]);
                    }
                    if (NPASS == 2 && h == 0) {
                        part[mt][r] = val;  // hold pass-0 mix in registers
                    } else {
                        if (NPASS == 2) val += part[mt][r];
                        if (DST == 0) {
                            if (ACT) val = elu_fast(val);
                            sDst[rl * dstr + col] = (half_t)val;
                        } else {
                            gOut[(size_t)(row0 + rl) * ldg + col] = val;
                        }
                    }
                }
        }
    }
}

// Logits layer: N=8, wave 0 only.
template <int CH>
__device__ __forceinline__ void layer_logits(
    const half_t* sSrc, int sstr, const half_t* __restrict__ W,
    const float* __restrict__ bias, float* sLog, int wv, int l15, int quad) {
    if (wv != 0) return;
    constexpr int K = CH * 32;
    float4v acc[2] = {(float4v){0.f, 0.f, 0.f, 0.f}, (float4v){0.f, 0.f, 0.f, 0.f}};
    const half_t* wb = &W[(size_t)l15 * K + quad * 8];
#pragma unroll
    for (int c = 0; c < CH; ++c) {
        half8 a0 = *(const half8*)&sSrc[l15 * sstr + c * 32 + quad * 8];
        half8 a1 = *(const half8*)&sSrc[(16 + l15) * sstr + c * 32 + quad * 8];
        half8 b = *(const half8*)&wb[c * 32];
        acc[0] = __builtin_amdgcn_mfma_f32_16x16x32_f16(a0, b, acc[0], 0, 0, 0);
        acc[1] = __builtin_amdgcn_mfma_f32_16x16x32_f16(a1, b, acc[1], 0, 0, 0);
    }
    if (l15 < 8) {
        const float bv = bias[l15];
#pragma unroll
        for (int mt = 0; mt < 2; ++mt)
#pragma unroll
            for (int r = 0; r < 4; ++r) {
                const int rl = mt * 16 + quad * 4 + r;
                sLog[rl * 8 + l15] = acc[mt][r] + bv;
            }
    }
}

__global__ __launch_bounds__(NT)
__attribute__((amdgpu_waves_per_eu(4, 4)))  // pin 4 waves/EU -> 128-VGPR budget
void fused_mann(
    const float* __restrict__ x, const float* __restrict__ z,
    const half_t* __restrict__ Wg0, const half_t* __restrict__ Wg1,
    const half_t* __restrict__ Wg2, const half_t* __restrict__ Wg3,
    const float* __restrict__ gb0, const float* __restrict__ gb1,
    const float* __restrict__ gb2, const float* __restrict__ gb3,
    const half_t* __restrict__ W0, const half_t* __restrict__ W1,
    const half_t* __restrict__ W2, const float* __restrict__ b0,
    const float* __restrict__ b1, const float* __restrict__ b2,
    float* __restrict__ out) {
    __shared__ __align__(16) half_t sA0[32 * 168];    // x||z (kept for expert L0)
    __shared__ __align__(16) half_t sBuf0[32 * 296];  // ping (z @256-287)
    __shared__ __align__(16) half_t sBuf1[32 * 296];  // pong (z @256-287)
    __shared__ float sLog[32 * 8];
    __shared__ float sCf[32 * 8];

    const int tid = threadIdx.x;
    const int row0 = blockIdx.x * 32;
    const int lane = tid & 63, wv = tid >> 6;  // wv 0..15
    const int l15 = lane & 15, quad = lane >> 4;

    for (int i = tid; i < 32 * 160; i += NT) {
        int r = i / 160, c = i % 160;
        float v = (c < 128) ? x[(size_t)(row0 + r) * 128 + c]
                            : z[(size_t)(row0 + r) * 32 + (c - 128)];
        sA0[r * 168 + c] = (half_t)v;
    }
    for (int i = tid; i < 32 * 32; i += NT) {
        int r = i >> 5, c = i & 31;
        half_t h = (half_t)z[(size_t)(row0 + r) * 32 + c];
        sBuf0[r * 296 + 256 + c] = h;
        sBuf1[r * 296 + 256 + c] = h;
    }
    __syncthreads();

    // Gating MLP: 16 strips over 16 waves
    layer_run<1, 1, 5, 16, 1, 0>(sA0, 168, Wg0, 256, gb0, 256, nullptr, sBuf0, 296,
                                 nullptr, 0, row0, wv, l15, quad);
    __syncthreads();
    layer_run<1, 1, 8, 16, 1, 0>(sBuf0, 296, Wg1, 256, gb1, 256, nullptr, sBuf1, 296,
                                 nullptr, 0, row0, wv, l15, quad);
    __syncthreads();
    layer_run<1, 1, 8, 16, 1, 0>(sBuf1, 296, Wg2, 256, gb2, 256, nullptr, sBuf0, 296,
                                 nullptr, 0, row0, wv, l15, quad);
    __syncthreads();
    layer_logits<8>(sBuf0, 296, Wg3, gb3, sLog, wv, l15, quad);
    __syncthreads();
    if (tid < 32) {
        float v[8], m = -1e30f;
#pragma unroll
        for (int e = 0; e < 8; ++e) { v[e] = sLog[tid * 8 + e]; m = fmaxf(m, v[e]); }
        float sum = 0.f;
#pragma unroll
        for (int e = 0; e < 8; ++e) { v[e] = __expf(v[e] - m); sum += v[e]; }
        float inv = 1.f / sum;
#pragma unroll
        for (int e = 0; e < 8; ++e) sCf[tid * 8 + e] = v[e] * inv;
    }
    __syncthreads();
    // Expert layers: 8 experts = 2 passes x 4, one strip per wave
    layer_run<4, 2, 5, 16, 1, 0>(sA0, 168, W0, 256, b0, 256, sCf, sBuf1, 296,
                                 nullptr, 0, row0, wv, l15, quad);
    __syncthreads();
    layer_run<4, 2, 9, 16, 1, 0>(sBuf1, 296, W1, 256, b1, 256, sCf, sBuf0, 296,
                                 nullptr, 0, row0, wv, l15, quad);
    __syncthreads();
    layer_run<4, 2, 9, 8, 0, 2>(sBuf0, 296, W2, 128, b2, 128, sCf, nullptr, 0,
                                out, 128, row0, wv, l15, quad);
}

// Weight prep (validated r5-r9): [E][K][N] fp32 -> [E][Npad][K] fp16, tiled transpose.
struct WDesc { const float* src; half_t* dst; int K, N, Npad, blk0; };
struct WPack { WDesc d[7]; };

__global__ __launch_bounds__(256) void conv_w_all(WPack pk) {
    __shared__ float t[32][33];
    const int bid = blockIdx.x;
    int di = 0;
#pragma unroll
    for (int i = 1; i < 7; ++i)
        if (bid >= pk.d[i].blk0) di = i;
    const WDesc d = pk.d[di];
    const int ntiles = d.Npad / 32, ktiles = d.K / 32;
    int local = bid - d.blk0;
    const int e = local / (ktiles * ntiles);
    local %= ktiles * ntiles;
    const int k0 = (local / ntiles) * 32, n0 = (local % ntiles) * 32;
    const int tr = threadIdx.x >> 3;
    const int tc = (threadIdx.x & 7) * 4;

    float4 v = {0.f, 0.f, 0.f, 0.f};
    if (n0 + tc < d.N)
        v = *(const float4*)&d.src[((size_t)e * d.K + k0 + tr) * d.N + n0 + tc];
    t[tr][tc] = v.x; t[tr][tc + 1] = v.y; t[tr][tc + 2] = v.z; t[tr][tc + 3] = v.w;
    __syncthreads();
    half4 h;
#pragma unroll
    for (int i = 0; i < 4; ++i) h[i] = (half_t)t[tc + i][tr];
    *(half4*)&d.dst[((size_t)e * d.Npad + n0 + tr) * d.K + k0 + tc] = h;
}

extern "C" void kernel_launch(void* const* d_in, const int* in_sizes, int n_in,
                              void* d_out, int out_size, void* d_ws, size_t ws_size,
                              hipStream_t stream) {
    const float* x   = (const float*)d_in[0];
    const float* z   = (const float*)d_in[1];
    const float* gw0 = (const float*)d_in[2];
    const float* gb0 = (const float*)d_in[3];
    const float* gw1 = (const float*)d_in[4];
    const float* gb1 = (const float*)d_in[5];
    const float* gw2 = (const float*)d_in[6];
    const float* gb2 = (const float*)d_in[7];
    const float* gw3 = (const float*)d_in[8];
    const float* gb3 = (const float*)d_in[9];
    const float* w0  = (const float*)d_in[10];
    const float* b0  = (const float*)d_in[11];
    const float* w1  = (const float*)d_in[12];
    const float* b1  = (const float*)d_in[13];
    const float* w2  = (const float*)d_in[14];
    const float* b2  = (const float*)d_in[15];

    char* p = (char*)d_ws;
    auto take = [&](size_t bytes) { char* r = p; p += bytes; return r; };
    half_t* Wg0 = (half_t*)take((size_t)256 * 160 * 2);
    half_t* Wg1 = (half_t*)take((size_t)256 * 256 * 2);
    half_t* Wg2 = (half_t*)take((size_t)256 * 256 * 2);
    half_t* Wg3 = (half_t*)take((size_t)32 * 256 * 2);
    half_t* W0  = (half_t*)take((size_t)8 * 256 * 160 * 2);
    half_t* W1  = (half_t*)take((size_t)8 * 256 * 288 * 2);
    half_t* W2  = (half_t*)take((size_t)8 * 128 * 288 * 2);
    float* out  = (float*)d_out;

    WPack pk;
    int blk = 0;
    auto mk = [&](int i, const float* s, half_t* dst, int K, int N, int Npad, int E) {
        pk.d[i] = WDesc{s, dst, K, N, Npad, blk};
        blk += E * (K / 32) * (Npad / 32);
    };
    mk(0, gw0, Wg0, 160, 256, 256, 1);
    mk(1, gw1, Wg1, 256, 256, 256, 1);
    mk(2, gw2, Wg2, 256, 256, 256, 1);
    mk(3, gw3, Wg3, 256, 8, 32, 1);
    mk(4, w0, W0, 160, 256, 256, 8);
    mk(5, w1, W1, 288, 256, 256, 8);
    mk(6, w2, W2, 288, 128, 128, 8);

    conv_w_all<<<dim3(blk), dim3(256), 0, stream>>>(pk);
    fused_mann<<<dim3(BSZ / 32), dim3(NT), 0, stream>>>(
        x, z, Wg0, Wg1, Wg2, Wg3, gb0, gb1, gb2, gb3,
        W0, W1, W2, b0, b1, b2, out);
}

// Round 11
// 156.821 us; speedup vs baseline: 1.2134x; 1.2134x over previous
//
#include <hip/hip_runtime.h>
#include <hip/hip_bf16.h>

typedef _Float16 half_t;
typedef __attribute__((ext_vector_type(8))) _Float16 half8;
typedef __attribute__((ext_vector_type(4))) _Float16 half4;
typedef __attribute__((ext_vector_type(4))) float float4v;

#define BSZ 8192
#define NT 512  // 8 waves/block, grid 256 -> 1 block/CU, 2 waves/SIMD, 128-VGPR budget (r7 precedent)

__device__ __forceinline__ float elu_fast(float v) {
    return v > 0.f ? v : (__expf(v) - 1.f);  // |err| ~1e-7, threshold 1.7e-3
}

// Flat (strip-phase, pass, chunk) pipeline over 8 waves. Wave wv owns strips
// {wv, wv+8, ...}. Experts split into NPASS passes of EXPP (live-register diet:
// bb[3][4]=48 + acc[4][2]=32 + aa 16 + part 8 + addr ~= 118 <= 128 -> no spill
// at NT=512, unlike r7's EXP=8 (176 nominal) or r8-r10's NT=1024 (64 budget)).
// B(it+2) register-prefetch crosses strip/pass boundaries; A(it+1) LDS dbuf.
// Pass-0 coef-mix held in regs; pass-1 adds, ELU, store. Single fp16 MFMA.
// DST 0: fp16->LDS (ACT=ELU opt). DST 2: fp32->global.
template <int EXPP, int NPASS, int CH, int NSTR, int ACT, int DST>
__device__ __forceinline__ void layer_run(
    const half_t* sSrc, int sstr, const half_t* __restrict__ W, int Npad,
    const float* __restrict__ bias, int biasN, const float* sCf,
    half_t* sDst, int dstr, float* __restrict__ gOut, int ldg,
    int row0, int wv, int l15, int quad) {
    constexpr int K = CH * 32;
    constexpr int SPW = NSTR / 8;
    constexpr int PC = NPASS * CH;
    constexpr int TOT = SPW * PC;
    const size_t estr = (size_t)Npad * K;
    const half_t* wbase = &W[(size_t)(wv * 16 + l15) * K + quad * 8];

    half8 bb[3][EXPP];
    half8 aa[2][2];
    float4v acc[EXPP][2];
    float part[2][4];

    // Preload B(0), B(1) (it=1 is p=0,h=0,c=1 since CH>=5), A(0)
#pragma unroll
    for (int e = 0; e < EXPP; ++e) bb[0][e] = *(const half8*)&wbase[(size_t)e * estr];
#pragma unroll
    for (int e = 0; e < EXPP; ++e) bb[1][e] = *(const half8*)&wbase[(size_t)e * estr + 32];
    aa[0][0] = *(const half8*)&sSrc[l15 * sstr + quad * 8];
    aa[0][1] = *(const half8*)&sSrc[(16 + l15) * sstr + quad * 8];

#pragma unroll
    for (int it = 0; it < TOT; ++it) {
        const int p = it / PC, rem = it - p * PC;
        const int h = rem / CH, c = rem - h * CH;
        if (it + 2 < TOT) {  // issue B(it+2) before compute(it)
            const int i2 = it + 2;
            const int p2 = i2 / PC, rem2 = i2 - p2 * PC;
            const int h2 = rem2 / CH, c2 = rem2 - h2 * CH;
            const half_t* wp =
                wbase + (size_t)(p2 * 8 * 16) * K + (size_t)(h2 * EXPP) * estr + c2 * 32;
#pragma unroll
            for (int e = 0; e < EXPP; ++e)
                bb[i2 % 3][e] = *(const half8*)&wp[(size_t)e * estr];
        }
        if (it + 1 < TOT) {  // A(it+1) from LDS (c is innermost: (it+1)%CH)
            const int c1n = (it + 1) % CH;
            aa[(it + 1) & 1][0] = *(const half8*)&sSrc[l15 * sstr + c1n * 32 + quad * 8];
            aa[(it + 1) & 1][1] =
                *(const half8*)&sSrc[(16 + l15) * sstr + c1n * 32 + quad * 8];
        }
        if (c == 0) {
#pragma unroll
            for (int e = 0; e < EXPP; ++e) {
                acc[e][0] = (float4v){0.f, 0.f, 0.f, 0.f};
                acc[e][1] = (float4v){0.f, 0.f, 0.f, 0.f};
            }
        }
#pragma unroll
        for (int e = 0; e < EXPP; ++e) {
            acc[e][0] = __builtin_amdgcn_mfma_f32_16x16x32_f16(aa[it & 1][0], bb[it % 3][e],
                                                               acc[e][0], 0, 0, 0);
            acc[e][1] = __builtin_amdgcn_mfma_f32_16x16x32_f16(aa[it & 1][1], bb[it % 3][e],
                                                               acc[e][1], 0, 0, 0);
        }
        if (c == CH - 1) {  // end of pass h for strip-phase p
            const int col = (wv + p * 8) * 16 + l15;
            const int eoff = h * EXPP;
            float bv[EXPP];
#pragma unroll
            for (int e = 0; e < EXPP; ++e) bv[e] = bias[(eoff + e) * biasN + col];
#pragma unroll
            for (int mt = 0; mt < 2; ++mt)
#pragma unroll
                for (int r = 0; r < 4; ++r) {
                    const int rl = mt * 16 + quad * 4 + r;
                    float val;
                    if (EXPP == 1) {
                        val = acc[0][mt][r] + bv[0];
                    } else {
                        val = 0.f;
#pragma unroll
                        for (int e = 0; e < EXPP; ++e)
                            val += sCf[rl * 8 + eoff + e] * (acc[e][mt][r] + bv[e]);
                    }
                    if (NPASS == 2 && h == 0) {
                        part[mt][r] = val;  // hold pass-0 mix in registers
                    } else {
                        if (NPASS == 2) val += part[mt][r];
                        if (DST == 0) {
                            if (ACT) val = elu_fast(val);
                            sDst[rl * dstr + col] = (half_t)val;
                        } else {
                            gOut[(size_t)(row0 + rl) * ldg + col] = val;
                        }
                    }
                }
        }
    }
}

// Logits layer: N=8, wave 0 only.
template <int CH>
__device__ __forceinline__ void layer_logits(
    const half_t* sSrc, int sstr, const half_t* __restrict__ W,
    const float* __restrict__ bias, float* sLog, int wv, int l15, int quad) {
    if (wv != 0) return;
    constexpr int K = CH * 32;
    float4v acc[2] = {(float4v){0.f, 0.f, 0.f, 0.f}, (float4v){0.f, 0.f, 0.f, 0.f}};
    const half_t* wb = &W[(size_t)l15 * K + quad * 8];
#pragma unroll
    for (int c = 0; c < CH; ++c) {
        half8 a0 = *(const half8*)&sSrc[l15 * sstr + c * 32 + quad * 8];
        half8 a1 = *(const half8*)&sSrc[(16 + l15) * sstr + c * 32 + quad * 8];
        half8 b = *(const half8*)&wb[c * 32];
        acc[0] = __builtin_amdgcn_mfma_f32_16x16x32_f16(a0, b, acc[0], 0, 0, 0);
        acc[1] = __builtin_amdgcn_mfma_f32_16x16x32_f16(a1, b, acc[1], 0, 0, 0);
    }
    if (l15 < 8) {
        const float bv = bias[l15];
#pragma unroll
        for (int mt = 0; mt < 2; ++mt)
#pragma unroll
            for (int r = 0; r < 4; ++r) {
                const int rl = mt * 16 + quad * 4 + r;
                sLog[rl * 8 + l15] = acc[mt][r] + bv;
            }
    }
}

__global__ __launch_bounds__(NT) void fused_mann(
    const float* __restrict__ x, const float* __restrict__ z,
    const half_t* __restrict__ Wg0, const half_t* __restrict__ Wg1,
    const half_t* __restrict__ Wg2, const half_t* __restrict__ Wg3,
    const float* __restrict__ gb0, const float* __restrict__ gb1,
    const float* __restrict__ gb2, const float* __restrict__ gb3,
    const half_t* __restrict__ W0, const half_t* __restrict__ W1,
    const half_t* __restrict__ W2, const float* __restrict__ b0,
    const float* __restrict__ b1, const float* __restrict__ b2,
    float* __restrict__ out) {
    __shared__ __align__(16) half_t sA0[32 * 168];    // x||z (kept for expert L0)
    __shared__ __align__(16) half_t sBuf0[32 * 296];  // ping (z @256-287)
    __shared__ __align__(16) half_t sBuf1[32 * 296];  // pong (z @256-287)
    __shared__ float sLog[32 * 8];
    __shared__ float sCf[32 * 8];

    const int tid = threadIdx.x;
    const int row0 = blockIdx.x * 32;
    const int lane = tid & 63, wv = tid >> 6;  // wv 0..7
    const int l15 = lane & 15, quad = lane >> 4;

    for (int i = tid; i < 32 * 160; i += NT) {
        int r = i / 160, c = i % 160;
        float v = (c < 128) ? x[(size_t)(row0 + r) * 128 + c]
                            : z[(size_t)(row0 + r) * 32 + (c - 128)];
        sA0[r * 168 + c] = (half_t)v;
    }
    for (int i = tid; i < 32 * 32; i += NT) {
        int r = i >> 5, c = i & 31;
        half_t h = (half_t)z[(size_t)(row0 + r) * 32 + c];
        sBuf0[r * 296 + 256 + c] = h;
        sBuf1[r * 296 + 256 + c] = h;
    }
    __syncthreads();

    // Gating MLP: 16 strips over 8 waves (2 strip-phases)
    layer_run<1, 1, 5, 16, 1, 0>(sA0, 168, Wg0, 256, gb0, 256, nullptr, sBuf0, 296,
                                 nullptr, 0, row0, wv, l15, quad);
    __syncthreads();
    layer_run<1, 1, 8, 16, 1, 0>(sBuf0, 296, Wg1, 256, gb1, 256, nullptr, sBuf1, 296,
                                 nullptr, 0, row0, wv, l15, quad);
    __syncthreads();
    layer_run<1, 1, 8, 16, 1, 0>(sBuf1, 296, Wg2, 256, gb2, 256, nullptr, sBuf0, 296,
                                 nullptr, 0, row0, wv, l15, quad);
    __syncthreads();
    layer_logits<8>(sBuf0, 296, Wg3, gb3, sLog, wv, l15, quad);
    __syncthreads();
    if (tid < 32) {
        float v[8], m = -1e30f;
#pragma unroll
        for (int e = 0; e < 8; ++e) { v[e] = sLog[tid * 8 + e]; m = fmaxf(m, v[e]); }
        float sum = 0.f;
#pragma unroll
        for (int e = 0; e < 8; ++e) { v[e] = __expf(v[e] - m); sum += v[e]; }
        float inv = 1.f / sum;
#pragma unroll
        for (int e = 0; e < 8; ++e) sCf[tid * 8 + e] = v[e] * inv;
    }
    __syncthreads();
    // Expert layers: 8 experts = 2 passes x 4
    layer_run<4, 2, 5, 16, 1, 0>(sA0, 168, W0, 256, b0, 256, sCf, sBuf1, 296,
                                 nullptr, 0, row0, wv, l15, quad);
    __syncthreads();
    layer_run<4, 2, 9, 16, 1, 0>(sBuf1, 296, W1, 256, b1, 256, sCf, sBuf0, 296,
                                 nullptr, 0, row0, wv, l15, quad);
    __syncthreads();
    layer_run<4, 2, 9, 8, 0, 2>(sBuf0, 296, W2, 128, b2, 128, sCf, nullptr, 0,
                                out, 128, row0, wv, l15, quad);
}

// Weight prep (validated r5-r10): [E][K][N] fp32 -> [E][Npad][K] fp16, tiled transpose.
struct WDesc { const float* src; half_t* dst; int K, N, Npad, blk0; };
struct WPack { WDesc d[7]; };

__global__ __launch_bounds__(256) void conv_w_all(WPack pk) {
    __shared__ float t[32][33];
    const int bid = blockIdx.x;
    int di = 0;
#pragma unroll
    for (int i = 1; i < 7; ++i)
        if (bid >= pk.d[i].blk0) di = i;
    const WDesc d = pk.d[di];
    const int ntiles = d.Npad / 32, ktiles = d.K / 32;
    int local = bid - d.blk0;
    const int e = local / (ktiles * ntiles);
    local %= ktiles * ntiles;
    const int k0 = (local / ntiles) * 32, n0 = (local % ntiles) * 32;
    const int tr = threadIdx.x >> 3;
    const int tc = (threadIdx.x & 7) * 4;

    float4 v = {0.f, 0.f, 0.f, 0.f};
    if (n0 + tc < d.N)
        v = *(const float4*)&d.src[((size_t)e * d.K + k0 + tr) * d.N + n0 + tc];
    t[tr][tc] = v.x; t[tr][tc + 1] = v.y; t[tr][tc + 2] = v.z; t[tr][tc + 3] = v.w;
    __syncthreads();
    half4 h;
#pragma unroll
    for (int i = 0; i < 4; ++i) h[i] = (half_t)t[tc + i][tr];
    *(half4*)&d.dst[((size_t)e * d.Npad + n0 + tr) * d.K + k0 + tc] = h;
}

extern "C" void kernel_launch(void* const* d_in, const int* in_sizes, int n_in,
                              void* d_out, int out_size, void* d_ws, size_t ws_size,
                              hipStream_t stream) {
    const float* x   = (const float*)d_in[0];
    const float* z   = (const float*)d_in[1];
    const float* gw0 = (const float*)d_in[2];
    const float* gb0 = (const float*)d_in[3];
    const float* gw1 = (const float*)d_in[4];
    const float* gb1 = (const float*)d_in[5];
    const float* gw2 = (const float*)d_in[6];
    const float* gb2 = (const float*)d_in[7];
    const float* gw3 = (const float*)d_in[8];
    const float* gb3 = (const float*)d_in[9];
    const float* w0  = (const float*)d_in[10];
    const float* b0  = (const float*)d_in[11];
    const float* w1  = (const float*)d_in[12];
    const float* b1  = (const float*)d_in[13];
    const float* w2  = (const float*)d_in[14];
    const float* b2  = (const float*)d_in[15];

    char* p = (char*)d_ws;
    auto take = [&](size_t bytes) { char* r = p; p += bytes; return r; };
    half_t* Wg0 = (half_t*)take((size_t)256 * 160 * 2);
    half_t* Wg1 = (half_t*)take((size_t)256 * 256 * 2);
    half_t* Wg2 = (half_t*)take((size_t)256 * 256 * 2);
    half_t* Wg3 = (half_t*)take((size_t)32 * 256 * 2);
    half_t* W0  = (half_t*)take((size_t)8 * 256 * 160 * 2);
    half_t* W1  = (half_t*)take((size_t)8 * 256 * 288 * 2);
    half_t* W2  = (half_t*)take((size_t)8 * 128 * 288 * 2);
    float* out  = (float*)d_out;

    WPack pk;
    int blk = 0;
    auto mk = [&](int i, const float* s, half_t* dst, int K, int N, int Npad, int E) {
        pk.d[i] = WDesc{s, dst, K, N, Npad, blk};
        blk += E * (K / 32) * (Npad / 32);
    };
    mk(0, gw0, Wg0, 160, 256, 256, 1);
    mk(1, gw1, Wg1, 256, 256, 256, 1);
    mk(2, gw2, Wg2, 256, 256, 256, 1);
    mk(3, gw3, Wg3, 256, 8, 32, 1);
    mk(4, w0, W0, 160, 256, 256, 8);
    mk(5, w1, W1, 288, 256, 256, 8);
    mk(6, w2, W2, 288, 128, 128, 8);

    conv_w_all<<<dim3(blk), dim3(256), 0, stream>>>(pk);
    fused_mann<<<dim3(BSZ / 32), dim3(NT), 0, stream>>>(
        x, z, Wg0, Wg1, Wg2, Wg3, gb0, gb1, gb2, gb3,
        W0, W1, W2, b0, b1, b2, out);
}